// Round 8
// baseline (275.521 us; speedup 1.0000x reference)
//
#include <hip/hip_runtime.h>

typedef unsigned short u16;
typedef __bf16 bf16x8 __attribute__((ext_vector_type(8)));
typedef float f32x4 __attribute__((ext_vector_type(4)));
typedef unsigned short u16x8 __attribute__((ext_vector_type(8)));

__device__ __forceinline__ u16 f2bf(float f) {
  unsigned u = __builtin_bit_cast(unsigned, f);
  u += 0x7fffu + ((u >> 16) & 1u);
  return (u16)(u >> 16);
}
__device__ __forceinline__ float b2f(u16 h) {
  return __builtin_bit_cast(float, (unsigned)h << 16);
}

// global -> LDS direct DMA, 16B per lane. LDS dest is wave-uniform base +
// lane*16 (m104), so the XOR swizzle lives on the SOURCE address (m173).
__device__ __forceinline__ void gld16(const u16* g, u16* l) {
  __builtin_amdgcn_global_load_lds((const __attribute__((address_space(1))) unsigned int*)g,
                                   (__attribute__((address_space(3))) unsigned int*)l, 16, 0, 0);
}

// ---------------------------------------------------------------------------
// Merged GroupNorm + weight-conversion dispatch (R5, measured).
// ---------------------------------------------------------------------------
#define GN_ROW 1026  // 1024 + 2 pad (odd word stride -> conflict-free)

__global__ __launch_bounds__(256) void gncvt_kernel(
    const float* __restrict__ x, const float* __restrict__ w, const float* __restrict__ bias,
    u16* __restrict__ hn,
    const float* __restrict__ qw, const float* __restrict__ kw, const float* __restrict__ vw,
    const float* __restrict__ pw, const float* __restrict__ qb, const float* __restrict__ kb,
    u16* __restrict__ wqk, u16* __restrict__ wv, u16* __restrict__ wp, float* __restrict__ qkb,
    float scale) {
  const int tid = threadIdx.x;
  if (blockIdx.x >= 512) {
    const int j = blockIdx.x - 512;
    const int yy = j >> 8, xx = j & 255;
    if (yy == 4) {
      int i = xx * 256 + tid;
      if (i < 512) qkb[i] = qb[i] * scale;
      else if (i < 1024) qkb[i] = kb[i - 512];
      return;
    }
    const float* s;
    u16* o;
    float sc = 1.f;
    switch (yy) {
      case 0: s = qw; o = wqk; sc = scale; break;
      case 1: s = kw; o = wqk + 262144; break;
      case 2: s = vw; o = wv; break;
      default: s = pw; o = wp; break;
    }
    int i = (xx * 256 + tid) * 4;
    float4 v = *(const float4*)(s + i);
    ushort4 pk = { f2bf(v.x * sc), f2bf(v.y * sc), f2bf(v.z * sc), f2bf(v.w * sc) };
    *(ushort4*)&o[i] = pk;
    return;
  }

  __shared__ u16 tile[16 * GN_ROW];
  __shared__ float red[18];
  const int bb = blockIdx.x & 15;
  const int g = blockIdx.x >> 4;
  const float4* xb = (const float4*)(x + ((size_t)bb * 512 + (size_t)g * 16) * 1024);

  float s = 0.f, sq = 0.f;
#pragma unroll
  for (int j = 0; j < 16; ++j) {
    float4 v = xb[j * 256 + tid];
    s += v.x + v.y + v.z + v.w;
    sq += v.x * v.x + v.y * v.y + v.z * v.z + v.w * v.w;
    int base = j * GN_ROW + tid * 4;
    ushort2 p0 = { f2bf(v.x), f2bf(v.y) };
    ushort2 p1 = { f2bf(v.z), f2bf(v.w) };
    *(ushort2*)&tile[base] = p0;
    *(ushort2*)&tile[base + 2] = p1;
  }
#pragma unroll
  for (int o = 32; o; o >>= 1) {
    s += __shfl_down(s, o, 64);
    sq += __shfl_down(sq, o, 64);
  }
  const int wv_ = tid >> 6;
  if ((tid & 63) == 0) { red[wv_] = s; red[wv_ + 4] = sq; }
  __syncthreads();
  if (tid == 0) {
    float S = red[0] + red[1] + red[2] + red[3];
    float Q = red[4] + red[5] + red[6] + red[7];
    float mean = S * (1.f / 16384.f);
    float var = Q * (1.f / 16384.f) - mean * mean;
    red[16] = mean;
    red[17] = rsqrtf(var + 1e-5f);
  }
  __syncthreads();
  const float mean = red[16], rstd = red[17];
  const int c0 = g * 16;

  float wf[16], bf_[16];
#pragma unroll
  for (int c = 0; c < 16; ++c) {
    float wc = w[c0 + c];
    wf[c] = wc * rstd;
    bf_[c] = bias[c0 + c] - mean * rstd * wc;
  }
#pragma unroll
  for (int it = 0; it < 4; ++it) {
    int hw = it * 256 + tid;
    u16x8 lo{}, hi{};
#pragma unroll
    for (int c = 0; c < 8; ++c) {
      lo[c] = f2bf(b2f(tile[c * GN_ROW + hw]) * wf[c] + bf_[c]);
      hi[c] = f2bf(b2f(tile[(c + 8) * GN_ROW + hw]) * wf[c + 8] + bf_[c + 8]);
    }
    u16* dst = hn + ((size_t)bb * 1024 + hw) * 512 + c0;
    *(u16x8*)dst = lo;
    *(u16x8*)(dst + 8) = hi;
  }
}

// ---------------------------------------------------------------------------
// R16: 8-phase-style NT GEMM (m201/T3+T4+T5 port) for the 256x256 gemms.
// 512 thr, 8 waves (2M x 4N), wave-tile 128x64, BK=32, 4-deep K-tile LDS
// ring (4 x 32KB = 128KB). Per K-tile: 4 phases, each =
//   {6 x ds_read_b128 (one C-quadrant's frags), 1 x gld16 (stage K-tile t+3
//    into slot (t+3)&3 = (t-1)&3, idle since t-1), [phase 3: counted
//    s_waitcnt vmcnt(8/4/0) -- NEVER drain mid-loop], s_barrier,
//    setprio(1), 8 x MFMA, setprio(0), s_barrier}.
// Ring safety: writes target the slot freed at t-1's last barrier; vmcnt(8)
// at t's phase 3 leaves only tiles t+2,t+3 in flight => t+1 landed before
// its first read. Known-good chunk-XOR swizzle (0 conflicts measured).
// ---------------------------------------------------------------------------
template <typename OutT>
__global__ __launch_bounds__(512, 2) void gemm8(
    const u16* __restrict__ A, const u16* __restrict__ Bt, OutT* __restrict__ C,
    const float* __restrict__ bias_m, const float* __restrict__ bias_n,
    int K, int lda, int ldb, int ldc, size_t sA, size_t sB, size_t sC,
    int T, int lognbx) {
  constexpr int ASZ = 256 * 32;  // u16 per A region of a slot
  constexpr int SLOT = 2 * ASZ;  // A + B
  __shared__ u16 ls[4 * SLOT];   // 128 KB ring

  // XCD-swizzle decode (batch z on XCD z%8)
  int fi = blockIdx.x;
  const int halfT = T << 3;
  const int h = (fi >= halfT);
  fi -= h * halfT;
  const int tile = fi >> 3;
  const int zb = (fi & 7) + (h << 3);
  const int bx = tile & ((1 << lognbx) - 1);
  const int by = tile >> lognbx;

  const int tid = threadIdx.x;
  const int lane = tid & 63;
  const int wave = tid >> 6;
  const int wm = wave >> 2, wn = wave & 3;  // 2 x 4 waves, wave-tile 128x64
  const int tm = by * 256, tn = bx * 256;
  const u16* Ab = A + (size_t)zb * sA;
  const u16* Bb = Bt + (size_t)zb * sB;
  const int q = lane >> 4, r = lane & 15;

  // staging maps: element e = tid + i*512 -> row=e>>2, LDS chunk sl=e&3
  // (linear dest e*16B); chunk sl holds global chunk g = sl ^ ((row>>1)&3).
  const u16* pA[2];
  const u16* pB[2];
  int aoff[2], boff[2];
#pragma unroll
  for (int i = 0; i < 2; ++i) {
    int e = tid + i * 512;
    int ra = e >> 2, sl = e & 3;
    int g = sl ^ ((ra >> 1) & 3);
    pA[i] = Ab + (size_t)(tm + ra) * lda + g * 8;
    pB[i] = Bb + (size_t)(tn + ra) * ldb + g * 8;
    aoff[i] = e * 8;
    boff[i] = ASZ + e * 8;
  }

  // fragment read offsets (swizzled; same involution as staging)
  int offA[8], offB[4];
#pragma unroll
  for (int mt = 0; mt < 8; ++mt) {
    int rowa = wm * 128 + mt * 16 + r;
    offA[mt] = rowa * 32 + (q ^ ((rowa >> 1) & 3)) * 8;
  }
#pragma unroll
  for (int nt = 0; nt < 4; ++nt) {
    int rowb = wn * 64 + nt * 16 + r;
    offB[nt] = ASZ + rowb * 32 + (q ^ ((rowb >> 1) & 3)) * 8;
  }

  const int nk = K >> 5;  // 16

  // prologue: stage K-tiles 0,1,2 into slots 0,1,2
#pragma unroll
  for (int t = 0; t < 3; ++t) {
    u16* S = ls + t * SLOT;
    const int k0 = t << 5;
#pragma unroll
    for (int i = 0; i < 2; ++i) gld16(pA[i] + k0, &S[aoff[i]]);
#pragma unroll
    for (int i = 0; i < 2; ++i) gld16(pB[i] + k0, &S[boff[i]]);
  }
  asm volatile("s_waitcnt vmcnt(8)" ::: "memory");  // tile 0 landed
  __builtin_amdgcn_s_barrier();

  f32x4 acc[8][4] = {};

  for (int t = 0; t < nk; ++t) {
    const u16* cs = ls + (t & 3) * SLOT;
    u16* SS = ls + ((t + 3) & 3) * SLOT;
    const bool st = (t + 3) < nk;
    const int k0 = (t + 3) << 5;
#pragma unroll
    for (int p = 0; p < 4; ++p) {
      const int mh = p >> 1, nh = p & 1;
      bf16x8 af[4], bf2[2];
#pragma unroll
      for (int m = 0; m < 4; ++m) af[m] = *(const bf16x8*)(const void*)&cs[offA[mh * 4 + m]];
#pragma unroll
      for (int n = 0; n < 2; ++n) bf2[n] = *(const bf16x8*)(const void*)&cs[offB[nh * 2 + n]];
      if (st) {
        if (p == 0) gld16(pA[0] + k0, &SS[aoff[0]]);
        else if (p == 1) gld16(pA[1] + k0, &SS[aoff[1]]);
        else if (p == 2) gld16(pB[0] + k0, &SS[boff[0]]);
        else gld16(pB[1] + k0, &SS[boff[1]]);
      }
      if (p == 3) {
        if (t + 3 < nk) {
          asm volatile("s_waitcnt vmcnt(8)" ::: "memory");
        } else if (t + 2 < nk) {
          asm volatile("s_waitcnt vmcnt(4)" ::: "memory");
        } else {
          asm volatile("s_waitcnt vmcnt(0)" ::: "memory");
        }
      }
      __builtin_amdgcn_s_barrier();
      __builtin_amdgcn_s_setprio(1);
#pragma unroll
      for (int m = 0; m < 4; ++m)
#pragma unroll
        for (int n = 0; n < 2; ++n)
          acc[mh * 4 + m][nh * 2 + n] =
              __builtin_amdgcn_mfma_f32_16x16x32_bf16(af[m], bf2[n], acc[mh * 4 + m][nh * 2 + n], 0, 0, 0);
      __builtin_amdgcn_s_setprio(0);
      __builtin_amdgcn_s_barrier();
    }
  }

  OutT* Cb = C + (size_t)zb * sC;
#pragma unroll
  for (int mt = 0; mt < 8; ++mt) {
#pragma unroll
    for (int nt = 0; nt < 4; ++nt) {
      const int col = tn + wn * 64 + nt * 16 + r;
      const float bn = bias_n ? bias_n[col] : 0.f;
#pragma unroll
      for (int reg = 0; reg < 4; ++reg) {
        const int row = tm + wm * 128 + mt * 16 + q * 4 + reg;
        float v = acc[mt][nt][reg];
        const float bm = bias_m ? bias_m[row] : 0.f;
        v = v + bm + bn;
        const size_t idx = (size_t)row * ldc + col;
        if constexpr (__is_same(OutT, u16)) Cb[idx] = f2bf(v);
        else Cb[idx] = v;
      }
    }
  }
}

// ---------------------------------------------------------------------------
// NT GEMM (R5 2-phase, BK=64, gld16) — control arm, used for V and out.
// ---------------------------------------------------------------------------
template <int BM, int BN, int TPB, int MINW, typename OutT>
__global__ __launch_bounds__(TPB, MINW) void gemm_nt(
    const u16* __restrict__ A, const u16* __restrict__ Bt, OutT* __restrict__ C,
    const float* __restrict__ bias_m, const float* __restrict__ bias_n, const float* __restrict__ res,
    int K, int lda, int ldb, int ldc, size_t sA, size_t sB, size_t sC, size_t sRes,
    int T, int lognbx) {
  constexpr int NW = TPB / 64;
  constexpr int WGN = BN / 64;
  constexpr int WGM = NW / WGN;
  constexpr int WTM = BM / WGM;
  constexpr int MT = WTM / 16;
  constexpr int ASLOT = 8 * BM / TPB;
  constexpr int BSLOT = 8 * BN / TPB;
  __shared__ u16 lsA[2][BM * 64];
  __shared__ u16 lsB[2][BN * 64];

  int fi = blockIdx.x;
  const int halfT = T << 3;
  const int h = (fi >= halfT);
  fi -= h * halfT;
  const int tile = fi >> 3;
  const int zb = (fi & 7) + (h << 3);
  const int bx = tile & ((1 << lognbx) - 1);
  const int by = tile >> lognbx;

  const int tid = threadIdx.x;
  const int lane = tid & 63;
  const int wave = tid >> 6;
  const int wm = wave / WGN, wn = wave % WGN;
  const int tm = by * BM, tn = bx * BN;
  const u16* Ab = A + (size_t)zb * sA;
  const u16* Bb = Bt + (size_t)zb * sB;

  f32x4 acc[MT][4] = {};
  const int q = lane >> 4, r = lane & 15;

  const u16* pA[ASLOT];
  const u16* pB[BSLOT];
#pragma unroll
  for (int i = 0; i < ASLOT; ++i) {
    int e = tid + i * TPB;
    int ra = e >> 3, sl = e & 7;
    int g = sl ^ ((ra >> 1) & 7);
    pA[i] = Ab + (size_t)(tm + ra) * lda + g * 8;
  }
#pragma unroll
  for (int i = 0; i < BSLOT; ++i) {
    int e = tid + i * TPB;
    int ra = e >> 3, sl = e & 7;
    int g = sl ^ ((ra >> 1) & 7);
    pB[i] = Bb + (size_t)(tn + ra) * ldb + g * 8;
  }

#pragma unroll
  for (int i = 0; i < ASLOT; ++i) gld16(pA[i], &lsA[0][(tid + i * TPB) * 8]);
#pragma unroll
  for (int i = 0; i < BSLOT; ++i) gld16(pB[i], &lsB[0][(tid + i * TPB) * 8]);
  __syncthreads();

  int offA[MT][2], offB[4][2];
#pragma unroll
  for (int mt = 0; mt < MT; ++mt) {
    int rowa = wm * WTM + mt * 16 + r;
#pragma unroll
    for (int ks = 0; ks < 2; ++ks)
      offA[mt][ks] = rowa * 64 + ((ks * 4 + q) ^ ((rowa >> 1) & 7)) * 8;
  }
#pragma unroll
  for (int nt = 0; nt < 4; ++nt) {
    int rowb = wn * 64 + nt * 16 + r;
#pragma unroll
    for (int ks = 0; ks < 2; ++ks)
      offB[nt][ks] = rowb * 64 + ((ks * 4 + q) ^ ((rowb >> 1) & 7)) * 8;
  }

  const int nk = K >> 6;
  for (int k = 0; k < nk; ++k) {
    const int cur = k & 1;
    if (k + 1 < nk) {
      const int k0 = (k + 1) << 6;
#pragma unroll
      for (int i = 0; i < ASLOT; ++i) gld16(pA[i] + k0, &lsA[cur ^ 1][(tid + i * TPB) * 8]);
#pragma unroll
      for (int i = 0; i < BSLOT; ++i) gld16(pB[i] + k0, &lsB[cur ^ 1][(tid + i * TPB) * 8]);
    }
#pragma unroll
    for (int ks = 0; ks < 2; ++ks) {
      bf16x8 af[MT], bfv[4];
#pragma unroll
      for (int mt = 0; mt < MT; ++mt) af[mt] = *(const bf16x8*)(const void*)&lsA[cur][offA[mt][ks]];
#pragma unroll
      for (int nt = 0; nt < 4; ++nt) bfv[nt] = *(const bf16x8*)(const void*)&lsB[cur][offB[nt][ks]];
#pragma unroll
      for (int mt = 0; mt < MT; ++mt)
#pragma unroll
        for (int nt = 0; nt < 4; ++nt)
          acc[mt][nt] = __builtin_amdgcn_mfma_f32_16x16x32_bf16(af[mt], bfv[nt], acc[mt][nt], 0, 0, 0);
    }
    __syncthreads();
  }

  OutT* Cb = C + (size_t)zb * sC;
  const float* Rb = res ? res + (size_t)zb * sRes : nullptr;
#pragma unroll
  for (int mt = 0; mt < MT; ++mt) {
#pragma unroll
    for (int nt = 0; nt < 4; ++nt) {
      const int col = tn + wn * 64 + nt * 16 + r;
      const float bn = bias_n ? bias_n[col] : 0.f;
#pragma unroll
      for (int reg = 0; reg < 4; ++reg) {
        const int row = tm + wm * WTM + mt * 16 + q * 4 + reg;
        float v = acc[mt][nt][reg];
        const float bm = bias_m ? bias_m[row] : 0.f;
        v = v + bm + bn;
        const size_t idx = (size_t)row * ldc + col;
        if (Rb) v += Rb[idx];
        if constexpr (__is_same(OutT, u16)) Cb[idx] = f2bf(v);
        else Cb[idx] = v;
      }
    }
  }
}

// ---------------------------------------------------------------------------
// Fused softmax + PV GEMM (R5, measured 43.5us). 256x128 tile, BK=64,
// K=1024, 512 thr. P = exp(S) staged directly (shift-invariance), row sums
// accumulated during staging, normalized in the epilogue.
// ---------------------------------------------------------------------------
__global__ __launch_bounds__(512, 2) void gemm_pv(const u16* __restrict__ S, const u16* __restrict__ V,
                                                  u16* __restrict__ O) {
  __shared__ u16 lsA[2][256 * 64];
  __shared__ u16 lsB[2][128 * 64];
  __shared__ float psum[2048];
  __shared__ float sinv[256];

  int fi = blockIdx.x;
  const int h = (fi >= 128);
  fi -= h * 128;
  const int tile = fi >> 3;
  const int zb = (fi & 7) + (h << 3);
  const int bx = tile & 3;
  const int by = tile >> 2;

  const int tid = threadIdx.x;
  const int lane = tid & 63;
  const int wave = tid >> 6;
  const int wm = wave >> 1, wn = wave & 1;
  const int tm = by * 256, tn = bx * 128;
  const u16* Ab = S + (size_t)zb * 1048576;
  const u16* Bb = V + (size_t)zb * 524288;

  const u16* pa[4];
  const u16* pb[2];
  int laoff[4], lboff[2];
#pragma unroll
  for (int i = 0; i < 4; ++i) {
    int e = tid + i * 512;
    int ra = e >> 3, sl = e & 7;
    int g = sl ^ ((ra >> 1) & 7);
    pa[i] = Ab + (size_t)(tm + ra) * 1024 + g * 8;
    laoff[i] = e * 8;
  }
#pragma unroll
  for (int i = 0; i < 2; ++i) {
    int e = tid + i * 512;
    int rb = e >> 3, sl = e & 7;
    int g = sl ^ ((rb >> 1) & 7);
    pb[i] = Bb + (size_t)(tn + rb) * 1024 + g * 8;
    lboff[i] = e * 8;
  }

  float ps[4] = {0.f, 0.f, 0.f, 0.f};

#pragma unroll
  for (int i = 0; i < 4; ++i) {
    u16x8 a0 = *(const u16x8*)pa[i];
    u16x8 t0;
    float loc = 0.f;
#pragma unroll
    for (int t = 0; t < 8; ++t) {
      float e_ = __expf(b2f(a0[t]));
      loc += e_;
      t0[t] = f2bf(e_);
    }
    ps[i] += loc;
    *(u16x8*)&lsA[0][laoff[i]] = t0;
  }
#pragma unroll
  for (int i = 0; i < 2; ++i) gld16(pb[i], &lsB[0][lboff[i]]);
  __syncthreads();

  const int q = lane >> 4, r = lane & 15;
  int offA[4][2], offB[4][2];
#pragma unroll
  for (int mt = 0; mt < 4; ++mt) {
    int rowa = wm * 64 + mt * 16 + r;
    int rowb = wn * 64 + mt * 16 + r;
#pragma unroll
    for (int ks = 0; ks < 2; ++ks) {
      offA[mt][ks] = rowa * 64 + ((ks * 4 + q) ^ ((rowa >> 1) & 7)) * 8;
      offB[mt][ks] = rowb * 64 + ((ks * 4 + q) ^ ((rowb >> 1) & 7)) * 8;
    }
  }

  f32x4 acc[4][4] = {};
  const int nk = 16;
  for (int k = 0; k < nk; ++k) {
    const int cur = k & 1;
    u16x8 an[4];
    if (k + 1 < nk) {
      const int k0 = (k + 1) << 6;
#pragma unroll
      for (int i = 0; i < 4; ++i) an[i] = *(const u16x8*)(pa[i] + k0);
#pragma unroll
      for (int i = 0; i < 2; ++i) gld16(pb[i] + k0, &lsB[cur ^ 1][lboff[i]]);
    }
#pragma unroll
    for (int ks = 0; ks < 2; ++ks) {
      bf16x8 af[4], bfv[4];
#pragma unroll
      for (int mt = 0; mt < 4; ++mt) af[mt] = *(const bf16x8*)(const void*)&lsA[cur][offA[mt][ks]];
#pragma unroll
      for (int nt = 0; nt < 4; ++nt) bfv[nt] = *(const bf16x8*)(const void*)&lsB[cur][offB[nt][ks]];
#pragma unroll
      for (int mt = 0; mt < 4; ++mt)
#pragma unroll
        for (int nt = 0; nt < 4; ++nt)
          acc[mt][nt] = __builtin_amdgcn_mfma_f32_16x16x32_bf16(af[mt], bfv[nt], acc[mt][nt], 0, 0, 0);
    }
    if (k + 1 < nk) {
#pragma unroll
      for (int i = 0; i < 4; ++i) {
        u16x8 t8;
        float loc = 0.f;
#pragma unroll
        for (int t = 0; t < 8; ++t) {
          float e_ = __expf(b2f(an[i][t]));
          loc += e_;
          t8[t] = f2bf(e_);
        }
        ps[i] += loc;
        *(u16x8*)&lsA[cur ^ 1][laoff[i]] = t8;
      }
    }
    __syncthreads();
  }

#pragma unroll
  for (int i = 0; i < 4; ++i) psum[tid + i * 512] = ps[i];
  __syncthreads();
  if (tid < 256) {
    float s = 0.f;
#pragma unroll
    for (int j = 0; j < 8; ++j) s += psum[tid * 8 + j];
    sinv[tid] = 1.f / s;
  }
  __syncthreads();

  u16* Ob = O + (size_t)zb * 524288;
#pragma unroll
  for (int mt = 0; mt < 4; ++mt) {
#pragma unroll
    for (int nt = 0; nt < 4; ++nt) {
      const int col = tn + wn * 64 + nt * 16 + r;
#pragma unroll
      for (int reg = 0; reg < 4; ++reg) {
        const int lrow = wm * 64 + mt * 16 + q * 4 + reg;
        Ob[(size_t)(tm + lrow) * 512 + col] = f2bf(acc[mt][nt][reg] * sinv[lrow]);
      }
    }
  }
}

// ---------------------------------------------------------------------------
extern "C" void kernel_launch(void* const* d_in, const int* in_sizes, int n_in,
                              void* d_out, int out_size, void* d_ws, size_t ws_size,
                              hipStream_t stream) {
  const float* x = (const float*)d_in[0];
  const float* gn_w = (const float*)d_in[2];
  const float* gn_b = (const float*)d_in[3];
  const float* q_w = (const float*)d_in[4];
  const float* q_b = (const float*)d_in[5];
  const float* k_w = (const float*)d_in[6];
  const float* k_b = (const float*)d_in[7];
  const float* v_w = (const float*)d_in[8];
  const float* v_b = (const float*)d_in[9];
  const float* p_w = (const float*)d_in[10];
  const float* p_b = (const float*)d_in[11];
  float* out = (float*)d_out;

  // workspace layout (u16 elements)
  u16* wqk = (u16*)d_ws;               // [1024,512]  (q scaled | k)
  u16* wv = wqk + 524288;              // [512,512]
  u16* wp = wv + 262144;               // [512,512]
  float* qkb = (float*)(wp + 262144);  // [1024] f32 combined bias
  u16* hn = wp + 262144 + 2048;        // [16,1024,512]
  u16* qkt = hn + 8388608;             // [16,1024,1024]  Q^T (scaled) | K^T
  u16* vv = qkt + 16777216;            // [16,512,1024]   V
  u16* ot = vv + 8388608;              // [16,1024,512]   O^T
  u16* Sb = ot + 8388608;              // [16,1024,1024]  raw scores

  const float inv_sqrt_c = 0.044194173824159216f;  // 512^-0.5
  const size_t sHN = 524288, sS = 1048576;

  gncvt_kernel<<<1792, 256, 0, stream>>>(x, gn_w, gn_b, hn, q_w, k_w, v_w, p_w, q_b, k_b,
                                         wqk, wv, wp, qkb, inv_sqrt_c);

  // QK^T[b] = Hn^T . [Wq';Wk]^T + qkb   [1024,1024]  256x256 8-phase, 16 tiles
  gemm8<u16><<<256, 512, 0, stream>>>(hn, wqk, qkt, nullptr, qkb,
                                      512, 512, 512, 1024, sHN, 0, sS, 16, 2);
  // V[b] = Wv . Hn + v_b                 [512,1024]  256x128 2-phase, 16 tiles
  gemm_nt<256, 128, 512, 2, u16><<<256, 512, 0, stream>>>(wv, hn, vv, v_b, nullptr, nullptr,
                                                          512, 512, 512, 1024, 0, sHN, sHN, 0, 16, 3);
  // S[b] = Q'^T . K  (raw scores)        [1024,1024] 256x256 8-phase, 16 tiles
  gemm8<u16><<<256, 512, 0, stream>>>(qkt, qkt + 512, Sb, nullptr, nullptr,
                                      512, 1024, 1024, 1024, sS, sS, sS, 16, 2);
  // O^T[b] = softmax(S) . V^T (fused)    [1024,512]  256x128, 16 tiles (4x4)
  gemm_pv<<<256, 512, 0, stream>>>(Sb, vv, ot);
  // out[b] = Wp . O + p_b + x            [512,1024] f32  256x128 2-phase
  gemm_nt<256, 128, 512, 2, float><<<256, 512, 0, stream>>>(wp, ot, out, p_b, nullptr, x,
                                                            512, 512, 512, 1024, 0, sHN, sHN, sHN, 16, 3);
}